// Round 1
// 770.265 us; speedup vs baseline: 1.2752x; 1.2752x over previous
//
#include <hip/hip_runtime.h>
#include <math.h>

#define TB   64
#define TT   255
#define TIN  32
#define NH   256
#define NE   128
#define NK   255
#define NPAD 127

// ---- spectral conv2 params ----
// Circular DFT length 384: linear-conv support [-127,381] aliases only into
// t in [257,383] mod 384, so the needed window t in [0,255) is exact.
#define NF    384
#define NBINS 193          // NF/2+1
#define NFC   386          // interleaved re/im component rows (2*NBINS)
#define HCH   64           // h-chunk size (4 chunks cover H=256)

typedef __attribute__((ext_vector_type(8))) short short8;
typedef __attribute__((ext_vector_type(4))) float float4v;

// ---- workspace layout (byte offsets) ----
#define WSB_WP1  0u            // 8,388,608  conv1 packed weights (dead after conv1)
#define WSB_Z    0u            // z aliases wp1 (written by idft, long after conv1)
#define WSB_W2S  8388608u      // 386*64*128*4 = 12,648,448  spectral W2 (one h-chunk)
#define WSB_HSP  21037056u     // 386*64*64*4  =  6,324,224  spectral hbn (one h-chunk)
#define WSB_ZSP  27361280u     // 386*64*128*4 = 12,648,448  spectral z accumulator
#define WSB_BD   40009728u     // 386*256*4 = 395,264  forward basis (time)
#define WSB_BW   40404992u     // 386*256*4            weight basis (k)
#define WSB_BI   40800256u     // 386*256*4            inverse basis
#define WSB_H    41811968u     // hf 16,777,216
#define WSB_HMID 41811968u     // hmid aliases hf (dead after DFT)
#define WSB_BN   58589184u     // 4 x 256 f32: sum1/sum2/sc/sh

// ---- output layout (float offsets) ----
#define O_AMP   0u
#define O_PHASE 8128u
#define O_FREQ  16320u
#define O_OFF   24448u

static __device__ __forceinline__ unsigned short f2bf(float f) {
  unsigned int u = __float_as_uint(f);
  unsigned int r = (u + 0x7FFFu + ((u >> 16) & 1u)) >> 16;
  return (unsigned short)r;
}
static __device__ __forceinline__ float bf2f(unsigned short s) {
  return __uint_as_float(((unsigned int)s) << 16);
}
static __device__ __forceinline__ short8 as_s8(uint4 v) {
  union { uint4 u; short8 s; } c; c.u = v; return c.s;
}

// ---------------- small init kernels ----------------
__global__ __launch_bounds__(256) void bn_zero_k(float* __restrict__ bn) {
  bn[threadIdx.x] = 0.f;
  bn[256 + threadIdx.x] = 0.f;
}

// DFT basis tables. Angle reduced with EXACT integer mod -> ~1e-7 accuracy.
// bd[2f][t]   =  cos(2*pi*f*t/384),  bd[2f+1][t] = -sin(...)        (forward DFT)
// bw[2f][k]   =  cos(2*pi*f*(k-127)/384), bw[2f+1][k] = +sin(...)   (weight DFT)
// bi[2f][t]   =  w*cos(2*pi*f*t/384)/384, bi[2f+1][t] = -w*sin(...)/384, w=2 (1 at f=0,192)
__global__ __launch_bounds__(256) void basis_init_k(float* __restrict__ bd,
                                                    float* __restrict__ bw,
                                                    float* __restrict__ bi) {
  const int m = blockIdx.x;          // 0..385 component row
  const int t = threadIdx.x;         // 0..255 (t or k column)
  const int f = m >> 1, im = m & 1;
  const float C = 6.28318530717958647692f / 384.f;
  int r1 = (f * t) % 384;
  float th1 = C * (float)r1;
  float s1 = sinf(th1), c1 = cosf(th1);
  bd[m * 256 + t] = im ? -s1 : c1;
  float wgt = (f == 0 || f == 192) ? 1.f : 2.f;
  bi[m * 256 + t] = (im ? -s1 * wgt : c1 * wgt) * (1.f / 384.f);
  int a = f * (t - 127);
  int r2 = a % 384; if (r2 < 0) r2 += 384;
  float th2 = C * (float)r2;
  bw[m * 256 + t] = im ? sinf(th2) : cosf(th2);
}

// ---------------- conv1 weight packing (hi/lo split) ----------------
// wp1[kk][et(16)][p(2)][lane][j]: split_p( w1[e=et*16+(lane&15)][i=(lane>>4)*8+j][kk] )
__global__ __launch_bounds__(256) void pack1_k(const float* __restrict__ w1,
                                               unsigned int* __restrict__ wp1u) {
  __shared__ float tile[512][33];
  const int et = blockIdx.x, kc = blockIdx.y;
  const int kk0 = kc * 32, cnt = min(32, NK - kk0);
  const int tid = threadIdx.x;
  for (int idx = tid; idx < 512 * 32; idx += 256) {
    int row = idx >> 5, kl = idx & 31;
    if (kl < cnt) {
      int e_l = row >> 5, i_l = row & 31;
      tile[row][kl] = w1[(size_t)((et * 16 + e_l) * TIN + i_l) * NK + kk0 + kl];
    }
  }
  __syncthreads();
  const int lane = tid >> 2, jp = (tid & 3) * 2;
  const int row0 = (lane & 15) * 32 + (lane >> 4) * 8 + jp;
  for (int kl = 0; kl < cnt; ++kl) {
    float w0 = tile[row0][kl], w1v = tile[row0 + 1][kl];
    unsigned short h0 = f2bf(w0), h1 = f2bf(w1v);
    unsigned short l0 = f2bf(w0 - bf2f(h0)), l1 = f2bf(w1v - bf2f(h1));
    size_t base = (size_t)(kk0 + kl) * 8192 + et * 512 + tid;
    wp1u[base] = (unsigned int)h0 | ((unsigned int)h1 << 16);
    wp1u[base + 256] = (unsigned int)l0 | ((unsigned int)l1 << 16);
  }
}

// ---------------- conv1 MFMA (split-bf16 3-term, depth-3 B ring) --------------
// grid (8 = 2 th x 4 chg, 64 b), 256 thr. Block: 128t x 64ch. Fused BN stats.
#define C1_ROWS 384
__global__ __launch_bounds__(256, 2) void conv1_mfma(
    const float* __restrict__ s, const unsigned int* __restrict__ wp1u,
    const float* __restrict__ b1v, float* __restrict__ hf, float* __restrict__ bn) {
  __shared__ __align__(16) unsigned short Alds[C1_ROWS * 64];   // 49152 B
  const int th = blockIdx.x & 1, chg = blockIdx.x >> 1, b = blockIdx.y;
  const int tid = threadIdx.x, lane = tid & 63, wv = tid >> 6;
  const int quad = lane >> 4, l15 = lane & 15;
  const int tg = wv & 1, eg = wv >> 1;
  unsigned int* Au = (unsigned int*)Alds;

  for (int idx = tid; idx < C1_ROWS * 16; idx += 256) {
    int r = idx >> 4, p = idx & 15;
    int t = th * 128 + r - NPAD;
    float v0 = 0.f, v1 = 0.f;
    if (t >= 0 && t < TT) {
      const float* sp = &s[(size_t)(b * TT + t) * TIN + p * 2];
      v0 = sp[0]; v1 = sp[1];
    }
    unsigned short h0 = f2bf(v0), h1 = f2bf(v1);
    unsigned short l0 = f2bf(v0 - bf2f(h0)), l1 = f2bf(v1 - bf2f(h1));
    int sw = r & 7;
    Au[r * 32 + ((((p >> 2) ^ sw) << 2) | (p & 3))] = (unsigned int)h0 | ((unsigned int)h1 << 16);
    Au[r * 32 + (((((p >> 2) + 4) ^ sw) << 2) | (p & 3))] = (unsigned int)l0 | ((unsigned int)l1 << 16);
  }

#define LOADB1(buf, KK) do {                                                      \
    const uint4* _b = (const uint4*)(wp1u + (size_t)(KK) * 8192u) +               \
                      (chg * 4 + eg * 2) * 128;                                   \
    buf[0] = _b[lane];          buf[1] = _b[64 + lane];                           \
    buf[2] = _b[128 + lane];    buf[3] = _b[192 + lane];                          \
  } while (0)

#define MSTEP1(KK, buf) do {                                                      \
    short8 bh0 = as_s8(buf[0]), bl0 = as_s8(buf[1]);                              \
    short8 bh1 = as_s8(buf[2]), bl1 = as_s8(buf[3]);                              \
    _Pragma("unroll")                                                             \
    for (int mi = 0; mi < 4; ++mi) {                                              \
      const int row = tg * 64 + mi * 16 + l15 + (KK);                             \
      const int sw = row & 7;                                                     \
      short8 ah = *(const short8*)&Alds[row * 64 + ((quad ^ sw) << 3)];           \
      short8 al = *(const short8*)&Alds[row * 64 + (((quad ^ 4) ^ sw) << 3)];     \
      acc[mi][0] = __builtin_amdgcn_mfma_f32_16x16x32_bf16(ah, bh0, acc[mi][0], 0, 0, 0); \
      acc[mi][0] = __builtin_amdgcn_mfma_f32_16x16x32_bf16(ah, bl0, acc[mi][0], 0, 0, 0); \
      acc[mi][0] = __builtin_amdgcn_mfma_f32_16x16x32_bf16(al, bh0, acc[mi][0], 0, 0, 0); \
      acc[mi][1] = __builtin_amdgcn_mfma_f32_16x16x32_bf16(ah, bh1, acc[mi][1], 0, 0, 0); \
      acc[mi][1] = __builtin_amdgcn_mfma_f32_16x16x32_bf16(ah, bl1, acc[mi][1], 0, 0, 0); \
      acc[mi][1] = __builtin_amdgcn_mfma_f32_16x16x32_bf16(al, bh1, acc[mi][1], 0, 0, 0); \
    }                                                                             \
  } while (0)

  uint4 b0[4], b1x[4], b2x[4];
  LOADB1(b0, 0);
  LOADB1(b1x, 1);
  LOADB1(b2x, 2);
  __syncthreads();

  float4v acc[4][2];
#pragma unroll
  for (int mi = 0; mi < 4; ++mi)
#pragma unroll
    for (int ni = 0; ni < 2; ++ni) acc[mi][ni] = (float4v)(0.f);

  for (int kp = 0; kp < 84; ++kp) {
    const int kk = kp * 3;
    MSTEP1(kk, b0);     LOADB1(b0, kk + 3);
    MSTEP1(kk + 1, b1x); LOADB1(b1x, kk + 4);
    MSTEP1(kk + 2, b2x); LOADB1(b2x, kk + 5);
  }
  MSTEP1(252, b0);
  MSTEP1(253, b1x);
  MSTEP1(254, b2x);

  // epilogue + fused BN partial sums
  float s1[2] = {0.f, 0.f}, s2[2] = {0.f, 0.f};
#pragma unroll
  for (int mi = 0; mi < 4; ++mi) {
#pragma unroll
    for (int ni = 0; ni < 2; ++ni) {
      int ch = chg * 64 + (eg * 2 + ni) * 16 + l15;
      float bias = b1v[ch];
#pragma unroll
      for (int r = 0; r < 4; ++r) {
        int t = th * 128 + tg * 64 + mi * 16 + quad * 4 + r;
        if (t < TT) {
          float v = fmaxf(acc[mi][ni][r] + bias, 0.f);
          hf[(size_t)(b * 256 + t) * NH + ch] = v;
          s1[ni] += v; s2[ni] += v * v;
        }
      }
    }
  }
#pragma unroll
  for (int ni = 0; ni < 2; ++ni) {
    s1[ni] += __shfl_xor(s1[ni], 16);
    s1[ni] += __shfl_xor(s1[ni], 32);
    s2[ni] += __shfl_xor(s2[ni], 16);
    s2[ni] += __shfl_xor(s2[ni], 32);
    if (quad == 0) {
      int ch = chg * 64 + (eg * 2 + ni) * 16 + l15;
      atomicAdd(&bn[ch], s1[ni]);
      atomicAdd(&bn[256 + ch], s2[ni]);
    }
  }
#undef LOADB1
#undef MSTEP1
}

__global__ __launch_bounds__(256) void bn_final_k(const float* __restrict__ gamma,
                                                  const float* __restrict__ beta,
                                                  float* __restrict__ bn) {
  const int h = threadIdx.x;
  const float inv = 1.0f / (TB * TT);
  float m = bn[h] * inv;
  float var = bn[256 + h] * inv - m * m;
  float sc = gamma[h] / sqrtf(var + 1e-5f);
  bn[512 + h] = sc;
  bn[768 + h] = beta[h] - m * sc;
}

// =============== spectral conv2 (fp32 tiled GEMMs) ======================
// Shared tile config: 64m x 64n output tile, 32-wide K tiles, 256 threads,
// 4x4 outputs per thread via float4 LDS reads (A broadcast across n-threads).

// outw[fc][hc*128+e] = sum_k bw[fc][k] * w2[e][h0+hc][k]   (one h-chunk)
__global__ __launch_bounds__(256) void w2prep_k(const float* __restrict__ w2,
                                                const float* __restrict__ bw,
                                                float* __restrict__ outw, int h0) {
  __shared__ __align__(16) float Al[32][68];
  __shared__ __align__(16) float Bl[32][68];
  const int tid = threadIdx.x;
  const int m0 = blockIdx.y * 64;          // fc tile (7 tiles cover 386)
  const int n0 = blockIdx.x * 64;          // n over 8192 = hc*128+e
  const int hc = n0 >> 7, e0 = n0 & 127;
  const int h = h0 + hc;
  const int tm = tid & 15, tn = tid >> 4;
  const int klA = tid & 31, mlA = tid >> 5;
  float acc[4][4];
#pragma unroll
  for (int i = 0; i < 4; ++i)
#pragma unroll
    for (int j = 0; j < 4; ++j) acc[i][j] = 0.f;

  for (int k0 = 0; k0 < NK; k0 += 32) {
    __syncthreads();
#pragma unroll
    for (int r = 0; r < 8; ++r) {
      int ml = r * 8 + mlA;
      int fc = m0 + ml;
      Al[klA][ml] = (fc < NFC) ? bw[fc * 256 + k0 + klA] : 0.f;
      int el = r * 8 + mlA;
      int k = k0 + klA;
      Bl[klA][el] = (k < NK) ? w2[((size_t)(e0 + el) * NH + h) * NK + k] : 0.f;
    }
    __syncthreads();
#pragma unroll
    for (int kt = 0; kt < 32; ++kt) {
      float4v a4 = *(const float4v*)&Al[kt][tm * 4];
      float4v b4 = *(const float4v*)&Bl[kt][tn * 4];
#pragma unroll
      for (int i = 0; i < 4; ++i)
#pragma unroll
        for (int j = 0; j < 4; ++j) acc[i][j] = fmaf(a4[i], b4[j], acc[i][j]);
    }
  }
#pragma unroll
  for (int i = 0; i < 4; ++i) {
    int fc = m0 + tm * 4 + i;
    if (fc < NFC) {
      float4v v; v[0] = acc[i][0]; v[1] = acc[i][1]; v[2] = acc[i][2]; v[3] = acc[i][3];
      *(float4v*)&outw[(size_t)fc * 8192 + n0 + tn * 4] = v;
    }
  }
}

// outh[fc][b*64+hc] = sum_t bd[fc][t] * (hf[b][t][h0+hc]*sc[h]+sh[h])
__global__ __launch_bounds__(256) void dft_k(const float* __restrict__ hf,
                                             const float* __restrict__ bn,
                                             const float* __restrict__ bd,
                                             float* __restrict__ outh, int h0) {
  __shared__ __align__(16) float Al[32][68];
  __shared__ __align__(16) float Bl[32][68];
  const int tid = threadIdx.x;
  const int m0 = blockIdx.y * 64;          // fc tile
  const int n0 = blockIdx.x * 64;          // n over 4096 = b*64+hc
  const int b = n0 >> 6;
  const int tm = tid & 15, tn = tid >> 4;
  const int klA = tid & 31, mlA = tid >> 5;
  const int nlB = tid & 63, klB4 = tid >> 6;
  const float scL = bn[512 + h0 + nlB];
  const float shL = bn[768 + h0 + nlB];
  float acc[4][4];
#pragma unroll
  for (int i = 0; i < 4; ++i)
#pragma unroll
    for (int j = 0; j < 4; ++j) acc[i][j] = 0.f;

  for (int k0 = 0; k0 < TT; k0 += 32) {
    __syncthreads();
#pragma unroll
    for (int r = 0; r < 8; ++r) {
      int ml = r * 8 + mlA;
      int fc = m0 + ml;
      Al[klA][ml] = (fc < NFC) ? bd[fc * 256 + k0 + klA] : 0.f;
    }
#pragma unroll
    for (int r = 0; r < 8; ++r) {
      int kl = r * 4 + klB4;
      int t = k0 + kl;
      Bl[kl][nlB] = (t < TT)
          ? fmaf(hf[((size_t)b * 256 + t) * NH + h0 + nlB], scL, shL) : 0.f;
    }
    __syncthreads();
#pragma unroll
    for (int kt = 0; kt < 32; ++kt) {
      float4v a4 = *(const float4v*)&Al[kt][tm * 4];
      float4v b4 = *(const float4v*)&Bl[kt][tn * 4];
#pragma unroll
      for (int i = 0; i < 4; ++i)
#pragma unroll
        for (int j = 0; j < 4; ++j) acc[i][j] = fmaf(a4[i], b4[j], acc[i][j]);
    }
  }
#pragma unroll
  for (int i = 0; i < 4; ++i) {
    int fc = m0 + tm * 4 + i;
    if (fc < NFC) {
      float4v v; v[0] = acc[i][0]; v[1] = acc[i][1]; v[2] = acc[i][2]; v[3] = acc[i][3];
      *(float4v*)&outh[(size_t)fc * 4096 + n0 + tn * 4] = v;
    }
  }
}

// Per-frequency complex GEMM over one h-chunk:
// zsp[2f][b*128+e] (+)= Re{ H[f][b][:] . W[f][:][e] },  zsp[2f+1][..] (+)= Im{..}
__global__ __launch_bounds__(256) void fgemm_k(const float* __restrict__ outh,
                                               const float* __restrict__ outw,
                                               float* __restrict__ zsp, int first) {
  __shared__ __align__(16) float Ar[32][68];
  __shared__ __align__(16) float Ai[32][68];
  __shared__ __align__(16) float Br[32][68];
  __shared__ __align__(16) float Bi[32][68];
  const int f = blockIdx.y;                // 0..192
  const int e0 = blockIdx.x * 64;          // 0 or 64
  const int tid = threadIdx.x;
  const int tb = tid & 15, te = tid >> 4;
  const int klA = tid & 31, blA8 = tid >> 5;
  const int nlB = tid & 63, klB4 = tid >> 6;
  const float* Hre = outh + (size_t)(2 * f) * 4096;
  const float* Him = Hre + 4096;
  const float* Wre = outw + (size_t)(2 * f) * 8192;
  const float* Wim = Wre + 8192;
  float accr[4][4], acci[4][4];
#pragma unroll
  for (int i = 0; i < 4; ++i)
#pragma unroll
    for (int j = 0; j < 4; ++j) { accr[i][j] = 0.f; acci[i][j] = 0.f; }

  for (int k0 = 0; k0 < HCH; k0 += 32) {
    __syncthreads();
#pragma unroll
    for (int r = 0; r < 8; ++r) {
      int bl = r * 8 + blA8;
      Ar[klA][bl] = Hre[bl * 64 + k0 + klA];
      Ai[klA][bl] = Him[bl * 64 + k0 + klA];
      int kl = r * 4 + klB4;
      Br[kl][nlB] = Wre[(k0 + kl) * 128 + e0 + nlB];
      Bi[kl][nlB] = Wim[(k0 + kl) * 128 + e0 + nlB];
    }
    __syncthreads();
#pragma unroll
    for (int kt = 0; kt < 32; ++kt) {
      float4v ar = *(const float4v*)&Ar[kt][tb * 4];
      float4v ai = *(const float4v*)&Ai[kt][tb * 4];
      float4v br = *(const float4v*)&Br[kt][te * 4];
      float4v bi = *(const float4v*)&Bi[kt][te * 4];
#pragma unroll
      for (int i = 0; i < 4; ++i)
#pragma unroll
        for (int j = 0; j < 4; ++j) {
          accr[i][j] = fmaf(ar[i], br[j], accr[i][j]);
          accr[i][j] = fmaf(-ai[i], bi[j], accr[i][j]);
          acci[i][j] = fmaf(ar[i], bi[j], acci[i][j]);
          acci[i][j] = fmaf(ai[i], br[j], acci[i][j]);
        }
    }
  }
  float* Zr = zsp + (size_t)(2 * f) * 8192;
  float* Zi = Zr + 8192;
#pragma unroll
  for (int i = 0; i < 4; ++i) {
    int b = tb * 4 + i;
    size_t off = (size_t)b * 128 + e0 + te * 4;
    float4v vr; vr[0] = accr[i][0]; vr[1] = accr[i][1]; vr[2] = accr[i][2]; vr[3] = accr[i][3];
    float4v vi; vi[0] = acci[i][0]; vi[1] = acci[i][1]; vi[2] = acci[i][2]; vi[3] = acci[i][3];
    if (first) {
      *(float4v*)&Zr[off] = vr;
      *(float4v*)&Zi[off] = vi;
    } else {
      float4v or_ = *(const float4v*)&Zr[off];
      float4v oi_ = *(const float4v*)&Zi[off];
      *(float4v*)&Zr[off] = or_ + vr;
      *(float4v*)&Zi[off] = oi_ + vi;
    }
  }
}

// z[be][t] = sum_fc zsp[fc][be] * bi[fc][t] + b2[e]
__global__ __launch_bounds__(256) void idft_k(const float* __restrict__ zsp,
                                              const float* __restrict__ bi,
                                              const float* __restrict__ b2,
                                              float* __restrict__ z) {
  __shared__ __align__(16) float Al[32][68];   // [k][m]
  __shared__ __align__(16) float Bl[32][68];   // [k][n]
  const int tid = threadIdx.x;
  const int m0 = blockIdx.x * 64;              // be tiles (128)
  const int n0 = blockIdx.y * 64;              // t tiles (4)
  const int tm = tid & 15, tn = tid >> 4;
  const int mlA = tid & 63, klA4 = tid >> 6;
  float acc[4][4];
#pragma unroll
  for (int i = 0; i < 4; ++i)
#pragma unroll
    for (int j = 0; j < 4; ++j) acc[i][j] = 0.f;

  for (int k0 = 0; k0 < NFC; k0 += 32) {       // 13 tiles (last partial)
    __syncthreads();
#pragma unroll
    for (int r = 0; r < 8; ++r) {
      int kl = r * 4 + klA4;
      int fc = k0 + kl;
      Al[kl][mlA] = (fc < NFC) ? zsp[(size_t)fc * 8192 + m0 + mlA] : 0.f;
      Bl[kl][mlA] = (fc < NFC) ? bi[fc * 256 + n0 + mlA] : 0.f;
    }
    __syncthreads();
#pragma unroll
    for (int kt = 0; kt < 32; ++kt) {
      float4v a4 = *(const float4v*)&Al[kt][tm * 4];
      float4v b4 = *(const float4v*)&Bl[kt][tn * 4];
#pragma unroll
      for (int i = 0; i < 4; ++i)
#pragma unroll
        for (int j = 0; j < 4; ++j) acc[i][j] = fmaf(a4[i], b4[j], acc[i][j]);
    }
  }
#pragma unroll
  for (int i = 0; i < 4; ++i) {
    int be = m0 + tm * 4 + i;
    float bv = b2[be & 127];
#pragma unroll
    for (int j = 0; j < 4; ++j) {
      int t = n0 + tn * 4 + j;
      if (t < TT) z[(size_t)be * TT + t] = acc[i][j] + bv;
    }
  }
}

// ---------------- MLP layer 1 (fp32) ----------------
__global__ __launch_bounds__(256) void mlp1_k(const float* __restrict__ z,
                                              const float* __restrict__ pw1,
                                              const float* __restrict__ pb1,
                                              float* __restrict__ hmid) {
  const int TC = 128;
  __shared__ float zl[TC * 68];
  __shared__ float pl[TC * 68];
  const int c = blockIdx.y, h0 = blockIdx.x * 64, tid = threadIdx.x;
  const int h4 = tid & 15, b4 = tid >> 4;
  float acc[4][4];
#pragma unroll
  for (int a = 0; a < 4; ++a)
#pragma unroll
    for (int bb = 0; bb < 4; ++bb) acc[a][bb] = 0.f;
  for (int t0 = 0; t0 < TT; t0 += TC) {
    const int tc = min(TC, TT - t0);
    __syncthreads();
    for (int idx = tid; idx < 64 * tc; idx += 256) {
      int r = idx / tc, t = idx - r * tc;
      zl[t * 68 + r] = z[(size_t)(r * NE + c) * TT + t0 + t];
      pl[t * 68 + r] = pw1[(size_t)(c * NH + h0 + r) * TT + t0 + t];
    }
    __syncthreads();
    for (int t = 0; t < tc; ++t) {
      float4 zv = *(const float4*)&zl[t * 68 + b4 * 4];
      float4 pv = *(const float4*)&pl[t * 68 + h4 * 4];
      float zz[4] = {zv.x, zv.y, zv.z, zv.w};
      float pp[4] = {pv.x, pv.y, pv.z, pv.w};
#pragma unroll
      for (int a = 0; a < 4; ++a)
#pragma unroll
        for (int bb = 0; bb < 4; ++bb) acc[a][bb] = fmaf(pp[a], zz[bb], acc[a][bb]);
    }
  }
#pragma unroll
  for (int a = 0; a < 4; ++a) {
    int hh = h0 + h4 * 4 + a;
    float bias = pb1[c * NH + hh];
#pragma unroll
    for (int bb = 0; bb < 4; ++bb) {
      int bidx = b4 * 4 + bb;
      float v = acc[a][bb] + bias;
      hmid[(size_t)(bidx * NE + c) * NH + hh] = fmaxf(v, 0.f);
    }
  }
}

// ---------------- MLP layer 2 + atan2 ----------------
__global__ __launch_bounds__(256) void mlp2_k(const float* __restrict__ hmid,
                                              const float* __restrict__ pw2,
                                              const float* __restrict__ pb2,
                                              float* __restrict__ out) {
  const int tid = threadIdx.x, lane = tid & 63, wv = tid >> 6;
  const int p = blockIdx.x * 4 + wv;
  const int b = p >> 7, c = p & 127;
  const float4 hv = *(const float4*)&hmid[(size_t)(b * NE + c) * NH + lane * 4];
  const float4 p0 = *(const float4*)&pw2[(size_t)(c * 2 + 0) * NH + lane * 4];
  const float4 p1 = *(const float4*)&pw2[(size_t)(c * 2 + 1) * NH + lane * 4];
  float s0 = hv.x * p0.x + hv.y * p0.y + hv.z * p0.z + hv.w * p0.w;
  float s1 = hv.x * p1.x + hv.y * p1.y + hv.z * p1.z + hv.w * p1.w;
#pragma unroll
  for (int off = 32; off; off >>= 1) {
    s0 += __shfl_down(s0, off);
    s1 += __shfl_down(s1, off);
  }
  if (lane == 0) {
    float a0 = s0 + pb2[c * 2 + 0];
    float a1 = s1 + pb2[c * 2 + 1];
    out[O_PHASE + b * NE + c] = atan2f(a1, a0);
  }
}

// ---------------- amplitude (Parseval) + constant frequency ----------------
__global__ __launch_bounds__(256) void amp_k(const float* __restrict__ z,
                                             float* __restrict__ out) {
  const int tid = threadIdx.x, lane = tid & 63, wv = tid >> 6;
  const int b = blockIdx.x, c = blockIdx.y * 4 + wv;
  const float* row = z + (size_t)(b * NE + c) * TT;
  float s1 = 0.f, s2 = 0.f;
  for (int idx = lane; idx < TT; idx += 64) {
    float v = row[idx];
    s1 += v; s2 += v * v;
  }
#pragma unroll
  for (int off = 32; off; off >>= 1) {
    s1 += __shfl_down(s1, off);
    s2 += __shfl_down(s2, off);
  }
  if (lane == 0 && c >= 1) {
    float P = 0.5f * (255.f * s2 + s1 * s1);
    out[O_AMP + b * 127 + (c - 1)] = 2.f * sqrtf(P) / 255.f;
    out[O_FREQ + b * 127 + (c - 1)] = (float)c / 255.f;
  }
}

// ---------------- offset: real rfft spectrum of channel 0 ----------------
__global__ __launch_bounds__(128) void offset_k(const float* __restrict__ z,
                                                float* __restrict__ out) {
  __shared__ float zr[TT];
  __shared__ float ct[TT];
  const int b = blockIdx.x, tid = threadIdx.x;
  for (int idx = tid; idx < TT; idx += 128) {
    zr[idx] = z[(size_t)(b * NE + 0) * TT + idx];
    ct[idx] = cosf(6.283185307179586f * (float)idx / 255.f);
  }
  __syncthreads();
  const int f = tid;
  float s = 0.f;
  int m = 0;
  for (int t = 0; t < TT; ++t) {
    s += zr[t] * ct[m];
    m += f; if (m >= TT) m -= TT;
  }
  out[O_OFF + b * NE + f] = s / 255.f;
}

extern "C" void kernel_launch(void* const* d_in, const int* in_sizes, int n_in,
                              void* d_out, int out_size, void* d_ws, size_t ws_size,
                              hipStream_t stream) {
  (void)in_sizes; (void)n_in; (void)out_size; (void)ws_size;
  const float* s       = (const float*)d_in[0];
  const float* conv1_w = (const float*)d_in[1];
  const float* conv1_b = (const float*)d_in[2];
  const float* bn_g    = (const float*)d_in[3];
  const float* bn_b    = (const float*)d_in[4];
  const float* conv2_w = (const float*)d_in[5];
  const float* conv2_b = (const float*)d_in[6];
  const float* pw1     = (const float*)d_in[7];
  const float* pb1     = (const float*)d_in[8];
  const float* pw2     = (const float*)d_in[9];
  const float* pb2     = (const float*)d_in[10];
  float* out = (float*)d_out;
  char* ws   = (char*)d_ws;

  unsigned int* wp1u = (unsigned int*)(ws + WSB_WP1);
  float* hf   = (float*)(ws + WSB_H);
  float* z    = (float*)(ws + WSB_Z);      // aliases wp1 (dead after conv1)
  float* bn   = (float*)(ws + WSB_BN);
  float* hmid = (float*)(ws + WSB_HMID);   // aliases hf (dead after dft)
  float* w2s  = (float*)(ws + WSB_W2S);
  float* hsp  = (float*)(ws + WSB_HSP);
  float* zsp  = (float*)(ws + WSB_ZSP);
  float* bd   = (float*)(ws + WSB_BD);
  float* bwt  = (float*)(ws + WSB_BW);
  float* bit  = (float*)(ws + WSB_BI);

  bn_zero_k<<<1, 256, 0, stream>>>(bn);
  basis_init_k<<<NFC, 256, 0, stream>>>(bd, bwt, bit);
  pack1_k<<<dim3(16, 8), 256, 0, stream>>>(conv1_w, wp1u);

  conv1_mfma<<<dim3(8, TB), 256, 0, stream>>>(s, wp1u, conv1_b, hf, bn);
  bn_final_k<<<1, 256, 0, stream>>>(bn_g, bn_b, bn);

  // spectral conv2, h-chunked (4 x 64 channels)
  for (int c = 0; c < 4; ++c) {
    w2prep_k<<<dim3(128, 7), 256, 0, stream>>>(conv2_w, bwt, w2s, c * HCH);
    dft_k<<<dim3(64, 7), 256, 0, stream>>>(hf, bn, bd, hsp, c * HCH);
    fgemm_k<<<dim3(2, NBINS), 256, 0, stream>>>(hsp, w2s, zsp, c == 0 ? 1 : 0);
  }
  idft_k<<<dim3(128, 4), 256, 0, stream>>>(zsp, bit, conv2_b, z);

  mlp1_k<<<dim3(4, NE), 256, 0, stream>>>(z, pw1, pb1, hmid);
  mlp2_k<<<TB * NE / 4, 256, 0, stream>>>(hmid, pw2, pb2, out);
  amp_k<<<dim3(TB, 32), 256, 0, stream>>>(z, out);
  offset_k<<<TB, 128, 0, stream>>>(z, out);
}

// Round 4
// 668.042 us; speedup vs baseline: 1.4703x; 1.1530x over previous
//
#include <hip/hip_runtime.h>
#include <math.h>

#define TB   64
#define TT   255
#define TIN  32
#define NH   256
#define NE   128
#define NK   255
#define NPAD 127

// ---- spectral conv2 params ----
// Circular DFT length 384: linear-conv support [-127,381] aliases only into
// t in [257,383] mod 384, so the needed window t in [0,255) is exact.
#define NF    384
#define NBINS 193          // NF/2+1
#define NFC   386          // interleaved re/im component rows (2*NBINS)
#define HCH   64           // h-chunk size (4 chunks cover H=256)

typedef __attribute__((ext_vector_type(8))) short short8;
typedef __attribute__((ext_vector_type(4))) float float4v;

// ---- workspace layout (byte offsets) ----
#define WSB_WP1  0u            // 8,388,608  conv1 packed weights (dead after conv1)
#define WSB_Z    0u            // z (8192*255*4 = 8,355,840) aliases wp1
#define WSB_W2S  8388608u      // 386*64*128*4 = 12,648,448  spectral W2 chunk [fc][hc*128+e]
#define WSB_HSP  21037056u     // 386*64*64*4  =  6,324,224  spectral hbn chunk [fc][b*64+hc]
#define WSB_ZSP  27361280u     // 386*64*128*4 = 12,648,448  spectral z accumulator
#define WSB_BD   40009728u     // 386*256*4 = 395,264  forward basis (time)
#define WSB_BW   40404992u     // 386*256*4            weight basis (k)
#define WSB_BI   40800256u     // 386*256*4            inverse basis
#define WSB_H    41811968u     // hf 16,777,216
#define WSB_HMID 41811968u     // hmid aliases hf (dead after DFT)
#define WSB_BN   58589184u     // 4 x 256 f32: sum1/sum2/sc/sh

// ---- output layout (float offsets) ----
#define O_AMP   0u
#define O_PHASE 8128u
#define O_FREQ  16320u
#define O_OFF   24448u

static __device__ __forceinline__ unsigned short f2bf(float f) {
  unsigned int u = __float_as_uint(f);
  unsigned int r = (u + 0x7FFFu + ((u >> 16) & 1u)) >> 16;
  return (unsigned short)r;
}
static __device__ __forceinline__ float bf2f(unsigned short s) {
  return __uint_as_float(((unsigned int)s) << 16);
}
static __device__ __forceinline__ short8 as_s8(uint4 v) {
  union { uint4 u; short8 s; } c; c.u = v; return c.s;
}

// split-bf16 staging: write 8 consecutive-k fp32 values (pairs p0..p0+3) of row r
// into swizzled LDS (hi slots {0..3}^sw, lo slots {4..7}^sw), matching conv1.
static __device__ __forceinline__ void stage8(unsigned int* __restrict__ U, int r,
                                              int p0, const float* __restrict__ v) {
  const int sw = r & 7;
  const int base = r * 32;
#pragma unroll
  for (int q = 0; q < 4; ++q) {
    float x0 = v[2 * q], x1 = v[2 * q + 1];
    unsigned short h0 = f2bf(x0), h1 = f2bf(x1);
    unsigned short l0 = f2bf(x0 - bf2f(h0)), l1 = f2bf(x1 - bf2f(h1));
    int p = p0 + q;
    U[base + ((((p >> 2) ^ sw) << 2) | (p & 3))] = (unsigned int)h0 | ((unsigned int)h1 << 16);
    U[base + (((((p >> 2) + 4) ^ sw) << 2) | (p & 3))] = (unsigned int)l0 | ((unsigned int)l1 << 16);
  }
}
// fragment read: part 0 = hi, 1 = lo
static __device__ __forceinline__ short8 frag(const unsigned short* __restrict__ lds,
                                              int row, int quad, int part) {
  return *(const short8*)&lds[row * 64 + (((quad ^ (part << 2)) ^ (row & 7)) << 3)];
}
#define MF(a, b, c) __builtin_amdgcn_mfma_f32_16x16x32_bf16((a), (b), (c), 0, 0, 0)

// ---------------- small init kernels ----------------
__global__ __launch_bounds__(256) void bn_zero_k(float* __restrict__ bn) {
  bn[threadIdx.x] = 0.f;
  bn[256 + threadIdx.x] = 0.f;
}

// DFT basis tables. Angle reduced with EXACT integer mod -> ~1e-7 accuracy.
// bd[2f][t]   =  cos(2*pi*f*t/384),  bd[2f+1][t] = -sin(...)        (forward DFT)
// bw[2f][k]   =  cos(2*pi*f*(k-127)/384), bw[2f+1][k] = +sin(...)   (weight DFT)
// bi[2f][t]   =  w*cos(2*pi*f*t/384)/384, bi[2f+1][t] = -w*sin(...)/384, w=2 (1 at f=0,192)
__global__ __launch_bounds__(256) void basis_init_k(float* __restrict__ bd,
                                                    float* __restrict__ bw,
                                                    float* __restrict__ bi) {
  const int m = blockIdx.x;          // 0..385 component row
  const int t = threadIdx.x;         // 0..255 (t or k column)
  const int f = m >> 1, im = m & 1;
  const float C = 6.28318530717958647692f / 384.f;
  int r1 = (f * t) % 384;
  float th1 = C * (float)r1;
  float s1 = sinf(th1), c1 = cosf(th1);
  bd[m * 256 + t] = im ? -s1 : c1;
  float wgt = (f == 0 || f == 192) ? 1.f : 2.f;
  bi[m * 256 + t] = (im ? -s1 * wgt : c1 * wgt) * (1.f / 384.f);
  int a = f * (t - 127);
  int r2 = a % 384; if (r2 < 0) r2 += 384;
  float th2 = C * (float)r2;
  bw[m * 256 + t] = im ? sinf(th2) : cosf(th2);
}

// ---------------- conv1 weight packing (hi/lo split) ----------------
__global__ __launch_bounds__(256) void pack1_k(const float* __restrict__ w1,
                                               unsigned int* __restrict__ wp1u) {
  __shared__ float tile[512][33];
  const int et = blockIdx.x, kc = blockIdx.y;
  const int kk0 = kc * 32, cnt = min(32, NK - kk0);
  const int tid = threadIdx.x;
  for (int idx = tid; idx < 512 * 32; idx += 256) {
    int row = idx >> 5, kl = idx & 31;
    if (kl < cnt) {
      int e_l = row >> 5, i_l = row & 31;
      tile[row][kl] = w1[(size_t)((et * 16 + e_l) * TIN + i_l) * NK + kk0 + kl];
    }
  }
  __syncthreads();
  const int lane = tid >> 2, jp = (tid & 3) * 2;
  const int row0 = (lane & 15) * 32 + (lane >> 4) * 8 + jp;
  for (int kl = 0; kl < cnt; ++kl) {
    float w0 = tile[row0][kl], w1v = tile[row0 + 1][kl];
    unsigned short h0 = f2bf(w0), h1 = f2bf(w1v);
    unsigned short l0 = f2bf(w0 - bf2f(h0)), l1 = f2bf(w1v - bf2f(h1));
    size_t base = (size_t)(kk0 + kl) * 8192 + et * 512 + tid;
    wp1u[base] = (unsigned int)h0 | ((unsigned int)h1 << 16);
    wp1u[base + 256] = (unsigned int)l0 | ((unsigned int)l1 << 16);
  }
}

// ---------------- conv1 MFMA (split-bf16 3-term, depth-3 B ring) --------------
#define C1_ROWS 384
__global__ __launch_bounds__(256, 2) void conv1_mfma(
    const float* __restrict__ s, const unsigned int* __restrict__ wp1u,
    const float* __restrict__ b1v, float* __restrict__ hf, float* __restrict__ bn) {
  __shared__ __align__(16) unsigned short Alds[C1_ROWS * 64];   // 49152 B
  const int th = blockIdx.x & 1, chg = blockIdx.x >> 1, b = blockIdx.y;
  const int tid = threadIdx.x, lane = tid & 63, wv = tid >> 6;
  const int quad = lane >> 4, l15 = lane & 15;
  const int tg = wv & 1, eg = wv >> 1;
  unsigned int* Au = (unsigned int*)Alds;

  for (int idx = tid; idx < C1_ROWS * 16; idx += 256) {
    int r = idx >> 4, p = idx & 15;
    int t = th * 128 + r - NPAD;
    float v0 = 0.f, v1 = 0.f;
    if (t >= 0 && t < TT) {
      const float* sp = &s[(size_t)(b * TT + t) * TIN + p * 2];
      v0 = sp[0]; v1 = sp[1];
    }
    unsigned short h0 = f2bf(v0), h1 = f2bf(v1);
    unsigned short l0 = f2bf(v0 - bf2f(h0)), l1 = f2bf(v1 - bf2f(h1));
    int sw = r & 7;
    Au[r * 32 + ((((p >> 2) ^ sw) << 2) | (p & 3))] = (unsigned int)h0 | ((unsigned int)h1 << 16);
    Au[r * 32 + (((((p >> 2) + 4) ^ sw) << 2) | (p & 3))] = (unsigned int)l0 | ((unsigned int)l1 << 16);
  }

#define LOADB1(buf, KK) do {                                                      \
    const uint4* _b = (const uint4*)(wp1u + (size_t)(KK) * 8192u) +               \
                      (chg * 4 + eg * 2) * 128;                                   \
    buf[0] = _b[lane];          buf[1] = _b[64 + lane];                           \
    buf[2] = _b[128 + lane];    buf[3] = _b[192 + lane];                          \
  } while (0)

#define MSTEP1(KK, buf) do {                                                      \
    short8 bh0 = as_s8(buf[0]), bl0 = as_s8(buf[1]);                              \
    short8 bh1 = as_s8(buf[2]), bl1 = as_s8(buf[3]);                              \
    _Pragma("unroll")                                                             \
    for (int mi = 0; mi < 4; ++mi) {                                              \
      const int row = tg * 64 + mi * 16 + l15 + (KK);                             \
      const int sw = row & 7;                                                     \
      short8 ah = *(const short8*)&Alds[row * 64 + ((quad ^ sw) << 3)];           \
      short8 al = *(const short8*)&Alds[row * 64 + (((quad ^ 4) ^ sw) << 3)];     \
      acc[mi][0] = MF(ah, bh0, acc[mi][0]);                                       \
      acc[mi][0] = MF(ah, bl0, acc[mi][0]);                                       \
      acc[mi][0] = MF(al, bh0, acc[mi][0]);                                       \
      acc[mi][1] = MF(ah, bh1, acc[mi][1]);                                       \
      acc[mi][1] = MF(ah, bl1, acc[mi][1]);                                       \
      acc[mi][1] = MF(al, bh1, acc[mi][1]);                                       \
    }                                                                             \
  } while (0)

  uint4 b0[4], b1x[4], b2x[4];
  LOADB1(b0, 0);
  LOADB1(b1x, 1);
  LOADB1(b2x, 2);
  __syncthreads();

  float4v acc[4][2];
#pragma unroll
  for (int mi = 0; mi < 4; ++mi)
#pragma unroll
    for (int ni = 0; ni < 2; ++ni) acc[mi][ni] = (float4v)(0.f);

  for (int kp = 0; kp < 84; ++kp) {
    const int kk = kp * 3;
    MSTEP1(kk, b0);     LOADB1(b0, kk + 3);
    MSTEP1(kk + 1, b1x); LOADB1(b1x, kk + 4);
    MSTEP1(kk + 2, b2x); LOADB1(b2x, kk + 5);
  }
  MSTEP1(252, b0);
  MSTEP1(253, b1x);
  MSTEP1(254, b2x);

  float s1[2] = {0.f, 0.f}, s2[2] = {0.f, 0.f};
#pragma unroll
  for (int mi = 0; mi < 4; ++mi) {
#pragma unroll
    for (int ni = 0; ni < 2; ++ni) {
      int ch = chg * 64 + (eg * 2 + ni) * 16 + l15;
      float bias = b1v[ch];
#pragma unroll
      for (int r = 0; r < 4; ++r) {
        int t = th * 128 + tg * 64 + mi * 16 + quad * 4 + r;
        if (t < TT) {
          float v = fmaxf(acc[mi][ni][r] + bias, 0.f);
          hf[(size_t)(b * 256 + t) * NH + ch] = v;
          s1[ni] += v; s2[ni] += v * v;
        }
      }
    }
  }
#pragma unroll
  for (int ni = 0; ni < 2; ++ni) {
    s1[ni] += __shfl_xor(s1[ni], 16);
    s1[ni] += __shfl_xor(s1[ni], 32);
    s2[ni] += __shfl_xor(s2[ni], 16);
    s2[ni] += __shfl_xor(s2[ni], 32);
    if (quad == 0) {
      int ch = chg * 64 + (eg * 2 + ni) * 16 + l15;
      atomicAdd(&bn[ch], s1[ni]);
      atomicAdd(&bn[256 + ch], s2[ni]);
    }
  }
#undef LOADB1
#undef MSTEP1
}

__global__ __launch_bounds__(256) void bn_final_k(const float* __restrict__ gamma,
                                                  const float* __restrict__ beta,
                                                  float* __restrict__ bn) {
  const int h = threadIdx.x;
  const float inv = 1.0f / (TB * TT);
  float m = bn[h] * inv;
  float var = bn[256 + h] * inv - m * m;
  float sc = gamma[h] / sqrtf(var + 1e-5f);
  bn[512 + h] = sc;
  bn[768 + h] = beta[h] - m * sc;
}

// ---------------- w2prep: split-bf16 MFMA version ----------------
// outw[fc][hc*128+e] = sum_k bw[fc][k] * w2[e][h0c+hc][k].
// Tile: 128 fc x 128 n (one hc slice per block-x), K = 256 (k=255 zero-padded
// on the B side; A may hold the k=255 basis value but multiplies 0).
__global__ __launch_bounds__(256, 2) void w2prep_mfma(
    const float* __restrict__ w2, const float* __restrict__ bw,
    float* __restrict__ outw, int h0c) {
  __shared__ __align__(16) unsigned short Alds[128 * 64];   // 16 KB
  __shared__ __align__(16) unsigned short Blds[128 * 64];   // 16 KB
  const int hc = blockIdx.x;            // 0..63, n = hc*128 + e
  const int m0 = blockIdx.y * 128;      // fc tile (4 tiles cover 386)
  const int tid = threadIdx.x, lane = tid & 63, wv = tid >> 6;
  const int quad = lane >> 4, l15 = lane & 15;
  const int wm = wv >> 1, wn = wv & 1;
  unsigned int* Au = (unsigned int*)Alds;
  unsigned int* Bu = (unsigned int*)Blds;

  float4v acc[4][4];
#pragma unroll
  for (int i = 0; i < 4; ++i)
#pragma unroll
    for (int j = 0; j < 4; ++j) acc[i][j] = (float4v)(0.f);

  const int rA = tid >> 1, hfA = tid & 1;   // 128 rows x 2 thr (16 k each)
  const int fcA = m0 + rA;
  const float* srcA = bw + fcA * 256;
  const int rB = tid >> 1, hfB = tid & 1;   // rB = e, 128 rows x 2 thr
  const float* srcB = w2 + ((size_t)(rB * NH + h0c + hc)) * NK;

  for (int kk = 0; kk < 8; ++kk) {
    const int k0 = kk * 32;
    if (kk) __syncthreads();
    {   // A: basis rows, aligned float4 (stride 256 floats)
      float va[16];
      if (fcA < NFC) {
        const float4* s4 = (const float4*)(srcA + k0 + hfA * 16);
        *(float4*)(va + 0) = s4[0]; *(float4*)(va + 4) = s4[1];
        *(float4*)(va + 8) = s4[2]; *(float4*)(va + 12) = s4[3];
      } else {
#pragma unroll
        for (int q = 0; q < 16; ++q) va[q] = 0.f;
      }
      stage8(Au, rA, hfA * 8, va);
      stage8(Au, rA, hfA * 8 + 4, va + 8);
    }
    {   // B: w2 rows (stride 255 floats, scalar loads, k<NK guard)
      float vb[16];
#pragma unroll
      for (int q = 0; q < 16; ++q) {
        int k = k0 + hfB * 16 + q;
        vb[q] = (k < NK) ? srcB[k] : 0.f;
      }
      stage8(Bu, rB, hfB * 8, vb);
      stage8(Bu, rB, hfB * 8 + 4, vb + 8);
    }
    __syncthreads();
    short8 bh[4], bl[4];
#pragma unroll
    for (int ni = 0; ni < 4; ++ni) {
      int rb = wn * 64 + ni * 16 + l15;
      bh[ni] = frag(Blds, rb, quad, 0);
      bl[ni] = frag(Blds, rb, quad, 1);
    }
#pragma unroll
    for (int mi = 0; mi < 4; ++mi) {
      int ra = wm * 64 + mi * 16 + l15;
      short8 ah = frag(Alds, ra, quad, 0);
      short8 al = frag(Alds, ra, quad, 1);
#pragma unroll
      for (int ni = 0; ni < 4; ++ni) {
        acc[mi][ni] = MF(ah, bh[ni], acc[mi][ni]);
        acc[mi][ni] = MF(ah, bl[ni], acc[mi][ni]);
        acc[mi][ni] = MF(al, bh[ni], acc[mi][ni]);
      }
    }
  }
#pragma unroll
  for (int mi = 0; mi < 4; ++mi) {
    int fc0 = m0 + wm * 64 + mi * 16 + quad * 4;
#pragma unroll
    for (int ni = 0; ni < 4; ++ni) {
      int n = hc * 128 + wn * 64 + ni * 16 + l15;
#pragma unroll
      for (int r = 0; r < 4; ++r) {
        if (fc0 + r < NFC) outw[(size_t)(fc0 + r) * 8192 + n] = acc[mi][ni][r];
      }
    }
  }
}

// outh[fc][b*64+hc] = sum_t bd[fc][t] * (hf[b][t][h0+hc]*sc[h]+sh[h])
__global__ __launch_bounds__(256) void dft_k(const float* __restrict__ hf,
                                             const float* __restrict__ bn,
                                             const float* __restrict__ bd,
                                             float* __restrict__ outh, int h0) {
  __shared__ __align__(16) float Al[32][68];
  __shared__ __align__(16) float Bl[32][68];
  const int tid = threadIdx.x;
  const int m0 = blockIdx.y * 64;          // fc tile
  const int n0 = blockIdx.x * 64;          // n over 4096 = b*64+hc
  const int b = n0 >> 6;
  const int tm = tid & 15, tn = tid >> 4;
  const int klA = tid & 31, mlA = tid >> 5;
  const int nlB = tid & 63, klB4 = tid >> 6;
  const float scL = bn[512 + h0 + nlB];
  const float shL = bn[768 + h0 + nlB];
  float acc[4][4];
#pragma unroll
  for (int i = 0; i < 4; ++i)
#pragma unroll
    for (int j = 0; j < 4; ++j) acc[i][j] = 0.f;

  for (int k0 = 0; k0 < TT; k0 += 32) {
    __syncthreads();
#pragma unroll
    for (int r = 0; r < 8; ++r) {
      int ml = r * 8 + mlA;
      int fc = m0 + ml;
      Al[klA][ml] = (fc < NFC) ? bd[fc * 256 + k0 + klA] : 0.f;
    }
#pragma unroll
    for (int r = 0; r < 8; ++r) {
      int kl = r * 4 + klB4;
      int t = k0 + kl;
      Bl[kl][nlB] = (t < TT)
          ? fmaf(hf[((size_t)b * 256 + t) * NH + h0 + nlB], scL, shL) : 0.f;
    }
    __syncthreads();
#pragma unroll
    for (int kt = 0; kt < 32; ++kt) {
      float4v a4 = *(const float4v*)&Al[kt][tm * 4];
      float4v b4 = *(const float4v*)&Bl[kt][tn * 4];
#pragma unroll
      for (int i = 0; i < 4; ++i)
#pragma unroll
        for (int j = 0; j < 4; ++j) acc[i][j] = fmaf(a4[i], b4[j], acc[i][j]);
    }
  }
#pragma unroll
  for (int i = 0; i < 4; ++i) {
    int fc = m0 + tm * 4 + i;
    if (fc < NFC) {
      float4v v; v[0] = acc[i][0]; v[1] = acc[i][1]; v[2] = acc[i][2]; v[3] = acc[i][3];
      *(float4v*)&outh[(size_t)fc * 4096 + n0 + tn * 4] = v;
    }
  }
}

// Per-frequency complex GEMM over one h-chunk:
// zsp[2f][b*128+e] (+)= Re{ H[f][b][:] . W[f][:][e] },  zsp[2f+1][..] (+)= Im{..}
__global__ __launch_bounds__(256) void fgemm_k(const float* __restrict__ outh,
                                               const float* __restrict__ outw,
                                               float* __restrict__ zsp, int first) {
  __shared__ __align__(16) float Ar[32][68];
  __shared__ __align__(16) float Ai[32][68];
  __shared__ __align__(16) float Br[32][68];
  __shared__ __align__(16) float Bi[32][68];
  const int f = blockIdx.y;                // 0..192
  const int e0 = blockIdx.x * 64;          // 0 or 64
  const int tid = threadIdx.x;
  const int tb = tid & 15, te = tid >> 4;
  const int klA = tid & 31, blA8 = tid >> 5;
  const int nlB = tid & 63, klB4 = tid >> 6;
  const float* Hre = outh + (size_t)(2 * f) * 4096;
  const float* Him = Hre + 4096;
  const float* Wre = outw + (size_t)(2 * f) * 8192;
  const float* Wim = Wre + 8192;
  float accr[4][4], acci[4][4];
#pragma unroll
  for (int i = 0; i < 4; ++i)
#pragma unroll
    for (int j = 0; j < 4; ++j) { accr[i][j] = 0.f; acci[i][j] = 0.f; }

  for (int k0 = 0; k0 < HCH; k0 += 32) {
    __syncthreads();
#pragma unroll
    for (int r = 0; r < 8; ++r) {
      int bl = r * 8 + blA8;
      Ar[klA][bl] = Hre[bl * 64 + k0 + klA];
      Ai[klA][bl] = Him[bl * 64 + k0 + klA];
      int kl = r * 4 + klB4;
      Br[kl][nlB] = Wre[(k0 + kl) * 128 + e0 + nlB];
      Bi[kl][nlB] = Wim[(k0 + kl) * 128 + e0 + nlB];
    }
    __syncthreads();
#pragma unroll
    for (int kt = 0; kt < 32; ++kt) {
      float4v ar = *(const float4v*)&Ar[kt][tb * 4];
      float4v ai = *(const float4v*)&Ai[kt][tb * 4];
      float4v br = *(const float4v*)&Br[kt][te * 4];
      float4v bi = *(const float4v*)&Bi[kt][te * 4];
#pragma unroll
      for (int i = 0; i < 4; ++i)
#pragma unroll
        for (int j = 0; j < 4; ++j) {
          accr[i][j] = fmaf(ar[i], br[j], accr[i][j]);
          accr[i][j] = fmaf(-ai[i], bi[j], accr[i][j]);
          acci[i][j] = fmaf(ar[i], bi[j], acci[i][j]);
          acci[i][j] = fmaf(ai[i], br[j], acci[i][j]);
        }
    }
  }
  float* Zr = zsp + (size_t)(2 * f) * 8192;
  float* Zi = Zr + 8192;
#pragma unroll
  for (int i = 0; i < 4; ++i) {
    int b = tb * 4 + i;
    size_t off = (size_t)b * 128 + e0 + te * 4;
    float4v vr; vr[0] = accr[i][0]; vr[1] = accr[i][1]; vr[2] = accr[i][2]; vr[3] = accr[i][3];
    float4v vi; vi[0] = acci[i][0]; vi[1] = acci[i][1]; vi[2] = acci[i][2]; vi[3] = acci[i][3];
    if (first) {
      *(float4v*)&Zr[off] = vr;
      *(float4v*)&Zi[off] = vi;
    } else {
      float4v or_ = *(const float4v*)&Zr[off];
      float4v oi_ = *(const float4v*)&Zi[off];
      *(float4v*)&Zr[off] = or_ + vr;
      *(float4v*)&Zi[off] = oi_ + vi;
    }
  }
}

// z[be][t] = sum_fc zsp[fc][be] * bi[fc][t] + b2[e]
__global__ __launch_bounds__(256) void idft_k(const float* __restrict__ zsp,
                                              const float* __restrict__ bi,
                                              const float* __restrict__ b2,
                                              float* __restrict__ z) {
  __shared__ __align__(16) float Al[32][68];   // [k][m]
  __shared__ __align__(16) float Bl[32][68];   // [k][n]
  const int tid = threadIdx.x;
  const int m0 = blockIdx.x * 64;              // be tiles (128)
  const int n0 = blockIdx.y * 64;              // t tiles (4)
  const int tm = tid & 15, tn = tid >> 4;
  const int mlA = tid & 63, klA4 = tid >> 6;
  float acc[4][4];
#pragma unroll
  for (int i = 0; i < 4; ++i)
#pragma unroll
    for (int j = 0; j < 4; ++j) acc[i][j] = 0.f;

  for (int k0 = 0; k0 < NFC; k0 += 32) {       // 13 tiles (last partial)
    __syncthreads();
#pragma unroll
    for (int r = 0; r < 8; ++r) {
      int kl = r * 4 + klA4;
      int fc = k0 + kl;
      Al[kl][mlA] = (fc < NFC) ? zsp[(size_t)fc * 8192 + m0 + mlA] : 0.f;
      Bl[kl][mlA] = (fc < NFC) ? bi[fc * 256 + n0 + mlA] : 0.f;
    }
    __syncthreads();
#pragma unroll
    for (int kt = 0; kt < 32; ++kt) {
      float4v a4 = *(const float4v*)&Al[kt][tm * 4];
      float4v b4 = *(const float4v*)&Bl[kt][tn * 4];
#pragma unroll
      for (int i = 0; i < 4; ++i)
#pragma unroll
        for (int j = 0; j < 4; ++j) acc[i][j] = fmaf(a4[i], b4[j], acc[i][j]);
    }
  }
#pragma unroll
  for (int i = 0; i < 4; ++i) {
    int be = m0 + tm * 4 + i;
    float bv = b2[be & 127];
#pragma unroll
    for (int j = 0; j < 4; ++j) {
      int t = n0 + tn * 4 + j;
      if (t < TT) z[(size_t)be * TT + t] = acc[i][j] + bv;
    }
  }
}

// ---------------- MLP layer 1 (fp32) ----------------
__global__ __launch_bounds__(256) void mlp1_k(const float* __restrict__ z,
                                              const float* __restrict__ pw1,
                                              const float* __restrict__ pb1,
                                              float* __restrict__ hmid) {
  const int TC = 128;
  __shared__ float zl[TC * 68];
  __shared__ float pl[TC * 68];
  const int c = blockIdx.y, h0 = blockIdx.x * 64, tid = threadIdx.x;
  const int h4 = tid & 15, b4 = tid >> 4;
  float acc[4][4];
#pragma unroll
  for (int a = 0; a < 4; ++a)
#pragma unroll
    for (int bb = 0; bb < 4; ++bb) acc[a][bb] = 0.f;
  for (int t0 = 0; t0 < TT; t0 += TC) {
    const int tc = min(TC, TT - t0);
    __syncthreads();
    for (int idx = tid; idx < 64 * tc; idx += 256) {
      int r = idx / tc, t = idx - r * tc;
      zl[t * 68 + r] = z[(size_t)(r * NE + c) * TT + t0 + t];
      pl[t * 68 + r] = pw1[(size_t)(c * NH + h0 + r) * TT + t0 + t];
    }
    __syncthreads();
    for (int t = 0; t < tc; ++t) {
      float4 zv = *(const float4*)&zl[t * 68 + b4 * 4];
      float4 pv = *(const float4*)&pl[t * 68 + h4 * 4];
      float zz[4] = {zv.x, zv.y, zv.z, zv.w};
      float pp[4] = {pv.x, pv.y, pv.z, pv.w};
#pragma unroll
      for (int a = 0; a < 4; ++a)
#pragma unroll
        for (int bb = 0; bb < 4; ++bb) acc[a][bb] = fmaf(pp[a], zz[bb], acc[a][bb]);
    }
  }
#pragma unroll
  for (int a = 0; a < 4; ++a) {
    int hh = h0 + h4 * 4 + a;
    float bias = pb1[c * NH + hh];
#pragma unroll
    for (int bb = 0; bb < 4; ++bb) {
      int bidx = b4 * 4 + bb;
      float v = acc[a][bb] + bias;
      hmid[(size_t)(bidx * NE + c) * NH + hh] = fmaxf(v, 0.f);
    }
  }
}

// ---------------- MLP layer 2 + atan2 ----------------
__global__ __launch_bounds__(256) void mlp2_k(const float* __restrict__ hmid,
                                              const float* __restrict__ pw2,
                                              const float* __restrict__ pb2,
                                              float* __restrict__ out) {
  const int tid = threadIdx.x, lane = tid & 63, wv = tid >> 6;
  const int p = blockIdx.x * 4 + wv;
  const int b = p >> 7, c = p & 127;
  const float4 hv = *(const float4*)&hmid[(size_t)(b * NE + c) * NH + lane * 4];
  const float4 p0 = *(const float4*)&pw2[(size_t)(c * 2 + 0) * NH + lane * 4];
  const float4 p1 = *(const float4*)&pw2[(size_t)(c * 2 + 1) * NH + lane * 4];
  float s0 = hv.x * p0.x + hv.y * p0.y + hv.z * p0.z + hv.w * p0.w;
  float s1 = hv.x * p1.x + hv.y * p1.y + hv.z * p1.z + hv.w * p1.w;
#pragma unroll
  for (int off = 32; off; off >>= 1) {
    s0 += __shfl_down(s0, off);
    s1 += __shfl_down(s1, off);
  }
  if (lane == 0) {
    float a0 = s0 + pb2[c * 2 + 0];
    float a1 = s1 + pb2[c * 2 + 1];
    out[O_PHASE + b * NE + c] = atan2f(a1, a0);
  }
}

// ---------------- amplitude (Parseval) + constant frequency ----------------
__global__ __launch_bounds__(256) void amp_k(const float* __restrict__ z,
                                             float* __restrict__ out) {
  const int tid = threadIdx.x, lane = tid & 63, wv = tid >> 6;
  const int b = blockIdx.x, c = blockIdx.y * 4 + wv;
  const float* row = z + (size_t)(b * NE + c) * TT;
  float s1 = 0.f, s2 = 0.f;
  for (int idx = lane; idx < TT; idx += 64) {
    float v = row[idx];
    s1 += v; s2 += v * v;
  }
#pragma unroll
  for (int off = 32; off; off >>= 1) {
    s1 += __shfl_down(s1, off);
    s2 += __shfl_down(s2, off);
  }
  if (lane == 0 && c >= 1) {
    float P = 0.5f * (255.f * s2 + s1 * s1);
    out[O_AMP + b * 127 + (c - 1)] = 2.f * sqrtf(P) / 255.f;
    out[O_FREQ + b * 127 + (c - 1)] = (float)c / 255.f;
  }
}

// ---------------- offset: real rfft spectrum of channel 0 ----------------
__global__ __launch_bounds__(128) void offset_k(const float* __restrict__ z,
                                                float* __restrict__ out) {
  __shared__ float zr[TT];
  __shared__ float ct[TT];
  const int b = blockIdx.x, tid = threadIdx.x;
  for (int idx = tid; idx < TT; idx += 128) {
    zr[idx] = z[(size_t)(b * NE + 0) * TT + idx];
    ct[idx] = cosf(6.283185307179586f * (float)idx / 255.f);
  }
  __syncthreads();
  const int f = tid;
  float s = 0.f;
  int m = 0;
  for (int t = 0; t < TT; ++t) {
    s += zr[t] * ct[m];
    m += f; if (m >= TT) m -= TT;
  }
  out[O_OFF + b * NE + f] = s / 255.f;
}

extern "C" void kernel_launch(void* const* d_in, const int* in_sizes, int n_in,
                              void* d_out, int out_size, void* d_ws, size_t ws_size,
                              hipStream_t stream) {
  (void)in_sizes; (void)n_in; (void)out_size; (void)ws_size;
  const float* s       = (const float*)d_in[0];
  const float* conv1_w = (const float*)d_in[1];
  const float* conv1_b = (const float*)d_in[2];
  const float* bn_g    = (const float*)d_in[3];
  const float* bn_b    = (const float*)d_in[4];
  const float* conv2_w = (const float*)d_in[5];
  const float* conv2_b = (const float*)d_in[6];
  const float* pw1     = (const float*)d_in[7];
  const float* pb1     = (const float*)d_in[8];
  const float* pw2     = (const float*)d_in[9];
  const float* pb2     = (const float*)d_in[10];
  float* out = (float*)d_out;
  char* ws   = (char*)d_ws;

  unsigned int* wp1u = (unsigned int*)(ws + WSB_WP1);
  float* hf   = (float*)(ws + WSB_H);
  float* z    = (float*)(ws + WSB_Z);      // aliases wp1 (dead after conv1)
  float* bn   = (float*)(ws + WSB_BN);
  float* hmid = (float*)(ws + WSB_HMID);   // aliases hf (dead after dft)
  float* w2s  = (float*)(ws + WSB_W2S);
  float* hsp  = (float*)(ws + WSB_HSP);
  float* zsp  = (float*)(ws + WSB_ZSP);
  float* bd   = (float*)(ws + WSB_BD);
  float* bwt  = (float*)(ws + WSB_BW);
  float* bit  = (float*)(ws + WSB_BI);

  bn_zero_k<<<1, 256, 0, stream>>>(bn);
  basis_init_k<<<NFC, 256, 0, stream>>>(bd, bwt, bit);
  pack1_k<<<dim3(16, 8), 256, 0, stream>>>(conv1_w, wp1u);

  conv1_mfma<<<dim3(8, TB), 256, 0, stream>>>(s, wp1u, conv1_b, hf, bn);
  bn_final_k<<<1, 256, 0, stream>>>(bn_g, bn_b, bn);

  // spectral conv2, h-chunked (4 x 64 channels); w2prep now MFMA
  for (int c = 0; c < 4; ++c) {
    w2prep_mfma<<<dim3(64, 4), 256, 0, stream>>>(conv2_w, bwt, w2s, c * HCH);
    dft_k<<<dim3(64, 7), 256, 0, stream>>>(hf, bn, bd, hsp, c * HCH);
    fgemm_k<<<dim3(2, NBINS), 256, 0, stream>>>(hsp, w2s, zsp, c == 0 ? 1 : 0);
  }
  idft_k<<<dim3(128, 4), 256, 0, stream>>>(zsp, bit, conv2_b, z);

  mlp1_k<<<dim3(4, NE), 256, 0, stream>>>(z, pw1, pb1, hmid);
  mlp2_k<<<TB * NE / 4, 256, 0, stream>>>(hmid, pw2, pb2, out);
  amp_k<<<dim3(TB, 32), 256, 0, stream>>>(z, out);
  offset_k<<<TB, 128, 0, stream>>>(z, out);
}